// Round 15
// baseline (69.613 us; speedup 1.0000x reference)
//
#include <hip/hip_runtime.h>
#include <hip/hip_bf16.h>
#include <hip/hip_fp16.h>
#include <cstdint>
#include <cstddef>

typedef __attribute__((ext_vector_type(8))) short short8;
typedef __attribute__((ext_vector_type(8))) unsigned short ushort8;
typedef __attribute__((ext_vector_type(4))) float f32x4;

#define NSEL 10   // top-10 by pd (w monotone in pd); key[0] also gives radius

__device__ __forceinline__ void gload_lds16(const void* g, void* l) {
  typedef const __attribute__((address_space(1))) void* gp_t;
  typedef __attribute__((address_space(3))) void* lp_t;
  __builtin_amdgcn_global_load_lds((gp_t)(unsigned long long)(uintptr_t)g,
                                   (lp_t)(unsigned int)(unsigned long long)(uintptr_t)l,
                                   16, 0, 0);
}

__device__ __forceinline__ unsigned short f2h_bits(float f) {
  __half h = __float2half(f);
  return *reinterpret_cast<unsigned short*>(&h);
}

__device__ __forceinline__ float h2f_bits(unsigned short us) {
  __half h = *reinterpret_cast<__half*>(&us);
  return __half2float(h);
}

// ---------- kernel 1: bf16 cast of feats + fp32 row squared-norms ----------
// Also resets the topk completion counter (block 0) for the last-block reduce.
__global__ __launch_bounds__(256)
void prep_kernel(const float* __restrict__ zi, const float* __restrict__ zj,
                 unsigned short* __restrict__ fb, float* __restrict__ sq,
                 unsigned* __restrict__ counter, int n, int d) {
  __shared__ float wred[4];
  const int row = blockIdx.x;
  const int t = threadIdx.x, lane = t & 63, wave = t >> 6;
  if (row == 0 && t == 0) *counter = 0;
  const float* src = (row < n) ? (zi + (size_t)row * d) : (zj + (size_t)(row - n) * d);
  float s = 0.f;
  for (int c = t; c < d; c += 256) {
    float v = src[c];
    s += v * v;
    __hip_bfloat16 h = __float2bfloat16(v);
    fb[(size_t)row * d + c] = *reinterpret_cast<const unsigned short*>(&h);
  }
#pragma unroll
  for (int o = 32; o; o >>= 1) s += __shfl_xor(s, o, 64);
  if (lane == 0) wred[wave] = s;
  __syncthreads();
  if (t == 0) sq[row] = ((wred[0] + wred[1]) + wred[2]) + wred[3];
}

// ---------- kernel 2: 256x256 counted-vmcnt double-buffered bf16 MFMA GEMM ----------
// (R14 form — best measured.) pd stores are NON-TEMPORAL: pd is write-once /
// read-once, so keep it out of L2.
__global__ __launch_bounds__(512)
void gemm_pd_kernel(const unsigned short* __restrict__ fb,
                    const float* __restrict__ sq,
                    __half* __restrict__ pdh, int b, int d) {
  __shared__ char smem[131072];        // 2 x (A 32KB + B 32KB) double buffer
  const int t = threadIdx.x;           // 0..511
  const int lane = t & 63;
  const int wave = t >> 6;             // 0..7
  const int wm = wave >> 2, wn = wave & 3;
  const int rowBase = blockIdx.y * 256;
  const int colBase = blockIdx.x * 256;
  const int l15 = lane & 15, l4 = lane >> 4;
  const int rsw = l15 & 7;
  const int nt = d >> 6;               // K-tiles of 64

  f32x4 acc[8][4] = {};

  auto stage_tile = [&](int bufOff, int kt) {
#pragma unroll
    for (int half = 0; half < 2; ++half) {
#pragma unroll
      for (int ab = 0; ab < 2; ++ab) {
#pragma unroll
        for (int i = 0; i < 2; ++i) {
          const int c = half * 1024 + i * 512 + t;   // 16B chunk id
          const int r = c >> 3;
          const int us = (c & 7) ^ (r & 7);          // pre-swizzled source unit
          const int gbase = (ab == 0) ? rowBase : colBase;
          gload_lds16(fb + (size_t)(gbase + r) * d + kt * 64 + us * 8,
                      smem + bufOff + ab * 32768 + c * 16);
        }
      }
    }
  };

  int curOff = 0;
  stage_tile(0, 0);

  for (int kt = 0; kt < nt; ++kt) {
    if (kt + 1 < nt) {
      stage_tile(curOff ^ 65536, kt + 1);
      asm volatile("s_waitcnt vmcnt(8)" ::: "memory");  // cur tile landed; next stays in flight
    } else {
      asm volatile("s_waitcnt vmcnt(0)" ::: "memory");
    }
    __builtin_amdgcn_s_barrier();
    __builtin_amdgcn_sched_barrier(0);

    const unsigned short* smA = (const unsigned short*)(smem + curOff);
    const unsigned short* smB = (const unsigned short*)(smem + curOff + 32768);
#pragma unroll
    for (int ks = 0; ks < 2; ++ks) {
      short8 bf[4];
#pragma unroll
      for (int nn = 0; nn < 4; ++nn)
        bf[nn] = *(const short8*)&smB[(wn * 64 + nn * 16 + l15) * 64 + (((ks * 4 + l4) ^ rsw) * 8)];
#pragma unroll
      for (int m = 0; m < 8; ++m) {
        short8 af = *(const short8*)&smA[(wm * 128 + m * 16 + l15) * 64 + (((ks * 4 + l4) ^ rsw) * 8)];
#pragma unroll
        for (int nn = 0; nn < 4; ++nn)
          acc[m][nn] = __builtin_amdgcn_mfma_f32_16x16x32_bf16(af, bf[nn], acc[m][nn], 0, 0, 0);
      }
    }
    __builtin_amdgcn_sched_barrier(0);
    __builtin_amdgcn_s_barrier();
    __builtin_amdgcn_sched_barrier(0);
    curOff ^= 65536;
  }

  // ---- stage d^2 tile into swizzled LDS (dbuf region reusable: 128KB = 256x256 fp16) ----
  unsigned short* tileC = (unsigned short*)smem;
#pragma unroll
  for (int m = 0; m < 8; ++m) {
    const int r0l = wm * 128 + m * 16 + l4 * 4;      // local row base (4 rows)
    const int gr0 = rowBase + r0l;
    const float sqr0 = sq[gr0], sqr1 = sq[gr0 + 1], sqr2 = sq[gr0 + 2], sqr3 = sq[gr0 + 3];
#pragma unroll
    for (int nn = 0; nn < 4; ++nn) {
      const int cl = wn * 64 + nn * 16 + l15;        // local col
      const int gc = colBase + cl;
      const float sqc = sq[gc];
      float d20 = fmaxf(sqr0 + sqc - 2.0f * acc[m][nn][0], 0.0f);
      float d21 = fmaxf(sqr1 + sqc - 2.0f * acc[m][nn][1], 0.0f);
      float d22 = fmaxf(sqr2 + sqc - 2.0f * acc[m][nn][2], 0.0f);
      float d23 = fmaxf(sqr3 + sqc - 2.0f * acc[m][nn][3], 0.0f);
      unsigned short b0 = (gr0 == gc) ? (unsigned short)0x7C00 : f2h_bits(d20);
      unsigned short b1 = (gr0 + 1 == gc) ? (unsigned short)0x7C00 : f2h_bits(d21);
      unsigned short b2 = (gr0 + 2 == gc) ? (unsigned short)0x7C00 : f2h_bits(d22);
      unsigned short b3 = (gr0 + 3 == gc) ? (unsigned short)0x7C00 : f2h_bits(d23);
#pragma unroll
      for (int rg = 0; rg < 4; ++rg) {
        const int rl = r0l + rg;
        const int dw = rl * 128 + (cl >> 1);
        const int phys = dw ^ (((rl >> 2) & 3) << 3);
        unsigned short bits = (rg == 0) ? b0 : (rg == 1) ? b1 : (rg == 2) ? b2 : b3;
        tileC[phys * 2 + (cl & 1)] = bits;
      }
    }
  }
  __syncthreads();

  // ---- coalesced row-major NT stores: 32 iters x (512 thr x 8B) = 128 KB ----
#pragma unroll
  for (int it2 = 0; it2 < 32; ++it2) {
    const int rl = it2 * 8 + (t >> 6);               // local row
    const int dwb = rl * 128 + (t & 63) * 2;         // even dword base
    const int phys = dwb ^ (((rl >> 2) & 3) << 3);   // XOR keeps dword pair adjacent
    const unsigned long long v = *(const unsigned long long*)((const char*)smem + (size_t)phys * 4);
    __builtin_nontemporal_store(v,
        (unsigned long long*)((char*)pdh + ((size_t)(rowBase + rl) * b + colBase + (t & 63) * 4) * 2));
  }
}

// ---------- kernel 3: wave-per-row top-10 select + loss + last-block reduce ----------
// NT loads for pd (read-once). Last block reproduces the final reduce in the
// identical summation order -> bit-identical output, one fewer dispatch.
// Requires b == 4096 (8 chunks x 64 lanes x 8), C == 128.
__global__ __launch_bounds__(256, 2)
void topk_loss_kernel(const __half* __restrict__ pdh,
                      const float* __restrict__ pi, const float* __restrict__ pj,
                      const int* __restrict__ labels,
                      float* __restrict__ rowsum,
                      unsigned* __restrict__ counter,
                      float* __restrict__ out,
                      int n, int C, int b) {
  __shared__ unsigned lastFlag;
  __shared__ float wredf[4];
  const int t = threadIdx.x, lane = t & 63, wave = t >> 6;
  const int row = blockIdx.x * 4 + wave;

  // ---- Phase A: load row of packed (fp16 d2, idx); top-10 by repeated wave argmin ----
  const ushort8* rowp = (const ushort8*)(pdh + (size_t)row * b);
  unsigned vv[8][8];
  unsigned cmin[8];
#pragma unroll
  for (int ch = 0; ch < 8; ++ch) {
    ushort8 h = __builtin_nontemporal_load(rowp + ch * 64 + lane);
    unsigned mn = 0xFFFFFFFFu;
#pragma unroll
    for (int j = 0; j < 8; ++j) {
      unsigned pk = ((unsigned)h[j] << 16) | (unsigned)(ch * 512 + lane * 8 + j);
      vv[ch][j] = pk;
      mn = min(mn, pk);
    }
    cmin[ch] = mn;
  }

  unsigned key[NSEL];   // packed (fp16 d2 | idx) of the 10 nearest, ascending
#pragma unroll
  for (int r = 0; r < NSEL; ++r) {
    unsigned best = cmin[0];
#pragma unroll
    for (int ch = 1; ch < 8; ++ch) best = min(best, cmin[ch]);
#pragma unroll
    for (int o = 32; o; o >>= 1) {
      unsigned q = __shfl_xor(best, o, 64);
      best = min(best, q);
    }
    key[r] = best;
    const int idx = (int)(best & 0xFFFFu);
    if (((idx >> 3) & 63) == lane) {       // owner invalidates + rebuilds its chunk-min
      const int ch = idx >> 9, jj = idx & 7;
#pragma unroll
      for (int cc = 0; cc < 8; ++cc) {
        if (cc == ch) {
          unsigned mn = 0xFFFFFFFFu;
#pragma unroll
          for (int j = 0; j < 8; ++j) {
            if (j == jj) vv[cc][j] = 0xFFFFFFFFu;
            mn = min(mn, vv[cc][j]);
          }
          cmin[cc] = mn;
        }
      }
    }
  }

  // ---- Phase B: radius + masked contributions (prob dot only on label match) ----
  const float r0 = sqrtf(h2f_bits((unsigned short)(key[0] >> 16)));   // 1-NN distance
  const float inv_r0 = 1.0f / r0;
  const int ri = (row < n) ? row : row - n;
  const int li = labels[ri];
  const float* pme = (row < n) ? (pi + (size_t)row * C) : (pj + (size_t)(row - n) * C);
  const float pr0 = pme[lane], pr1 = pme[lane + 64];

  float tot = 0.f;
#pragma unroll
  for (int k = 0; k < NSEL; ++k) {
    const int j = (int)(key[k] & 0xFFFFu);
    const int rj = (j < n) ? j : j - n;
    const int lj = labels[rj];
    const bool m = (li != -1) & (lj != -1) & (li == lj) & (ri != rj);
    if (m) {   // identical across lanes -> uniform branch; ~0.08 hits/row expected
      const float* q = (j < n) ? (pi + (size_t)j * C) : (pj + (size_t)(j - n) * C);
      float part = pr0 * q[lane] + pr1 * q[lane + 64];
#pragma unroll
      for (int o = 32; o; o >>= 1) part += __shfl_xor(part, o, 64);
      const float pd = sqrtf(h2f_bits((unsigned short)(key[k] >> 16)));
      const float w = 1.0f - fminf(fmaxf((pd - r0) * inv_r0, 0.0f), 1.0f);
      tot += w * part;
    }
  }
  if (lane == 0) rowsum[row] = tot;

  // ---- last-block final reduce (bit-identical order to the old kernel 4) ----
  __syncthreads();
  if (t == 0) {
    __threadfence();
    const unsigned old = atomicAdd(counter, 1u);
    lastFlag = (old == (unsigned)(b / 4 - 1)) ? 1u : 0u;
  }
  __syncthreads();
  if (lastFlag) {
    __threadfence();
    float s = 0.f;
    for (int c = t; c < b; c += 256) s += rowsum[c];
#pragma unroll
    for (int o = 32; o; o >>= 1) s += __shfl_xor(s, o, 64);
    if (lane == 0) wredf[wave] = s;
    __syncthreads();
    if (t == 0) {
      float tt = ((wredf[0] + wredf[1]) + wredf[2]) + wredf[3];
      out[0] = tt / ((float)b * (float)b);
    }
  }
}

extern "C" void kernel_launch(void* const* d_in, const int* in_sizes, int n_in,
                              void* d_out, int out_size, void* d_ws, size_t ws_size,
                              hipStream_t stream) {
  const float* zi = (const float*)d_in[0];
  const float* zj = (const float*)d_in[1];
  const float* pi = (const float*)d_in[2];
  const float* pj = (const float*)d_in[3];
  const int* labels = (const int*)d_in[4];

  const int n = in_sizes[4];          // 2048
  const int d = in_sizes[0] / n;      // 512
  const int C = in_sizes[2] / n;      // 128
  const int b = 2 * n;                // 4096

  char* ws = (char*)d_ws;
  size_t off = 0;
  unsigned short* fb = (unsigned short*)(ws + off);
  off += ((size_t)b * d * 2 + 255) & ~(size_t)255;
  float* sq = (float*)(ws + off);
  off += ((size_t)b * 4 + 255) & ~(size_t)255;
  float* rowsum = (float*)(ws + off);
  off += ((size_t)b * 4 + 255) & ~(size_t)255;
  unsigned* counter = (unsigned*)(ws + off);
  off += 256;
  __half* pdh = (__half*)(ws + off);
  off += (size_t)b * b * 2;
  if (ws_size < off) return;  // workspace too small — bail rather than corrupt

  prep_kernel<<<b, 256, 0, stream>>>(zi, zj, fb, sq, counter, n, d);
  dim3 grid(b / 256, b / 256);
  gemm_pd_kernel<<<grid, 512, 0, stream>>>(fb, sq, pdh, b, d);
  topk_loss_kernel<<<b / 4, 256, 0, stream>>>(pdh, pi, pj, labels, rowsum, counter,
                                              (float*)d_out, n, C, b);
}

// Round 16
// 68.001 us; speedup vs baseline: 1.0237x; 1.0237x over previous
//
#include <hip/hip_runtime.h>
#include <hip/hip_bf16.h>
#include <hip/hip_fp16.h>
#include <cstdint>
#include <cstddef>

typedef __attribute__((ext_vector_type(8))) short short8;
typedef __attribute__((ext_vector_type(8))) unsigned short ushort8;
typedef __attribute__((ext_vector_type(4))) float f32x4;

#define NSEL 10   // top-10 by pd (w monotone in pd); key[0] also gives radius

__device__ __forceinline__ void gload_lds16(const void* g, void* l) {
  typedef const __attribute__((address_space(1))) void* gp_t;
  typedef __attribute__((address_space(3))) void* lp_t;
  __builtin_amdgcn_global_load_lds((gp_t)(unsigned long long)(uintptr_t)g,
                                   (lp_t)(unsigned int)(unsigned long long)(uintptr_t)l,
                                   16, 0, 0);
}

__device__ __forceinline__ unsigned short f2h_bits(float f) {
  __half h = __float2half(f);
  return *reinterpret_cast<unsigned short*>(&h);
}

__device__ __forceinline__ float h2f_bits(unsigned short us) {
  __half h = *reinterpret_cast<__half*>(&us);
  return __half2float(h);
}

// ---------- kernel 1: bf16 cast of feats + fp32 row squared-norms ----------
// Also resets the topk completion counter (block 0) for the last-block reduce.
__global__ __launch_bounds__(256)
void prep_kernel(const float* __restrict__ zi, const float* __restrict__ zj,
                 unsigned short* __restrict__ fb, float* __restrict__ sq,
                 unsigned* __restrict__ counter, int n, int d) {
  __shared__ float wred[4];
  const int row = blockIdx.x;
  const int t = threadIdx.x, lane = t & 63, wave = t >> 6;
  if (row == 0 && t == 0) *counter = 0;
  const float* src = (row < n) ? (zi + (size_t)row * d) : (zj + (size_t)(row - n) * d);
  float s = 0.f;
  for (int c = t; c < d; c += 256) {
    float v = src[c];
    s += v * v;
    __hip_bfloat16 h = __float2bfloat16(v);
    fb[(size_t)row * d + c] = *reinterpret_cast<const unsigned short*>(&h);
  }
#pragma unroll
  for (int o = 32; o; o >>= 1) s += __shfl_xor(s, o, 64);
  if (lane == 0) wred[wave] = s;
  __syncthreads();
  if (t == 0) sq[row] = ((wred[0] + wred[1]) + wred[2]) + wred[3];
}

// ---------- kernel 2: 256x256 counted-vmcnt double-buffered bf16 MFMA GEMM ----------
// (R14 form — best measured. No NT hints: pd is L2/L3-served on the re-read.)
__global__ __launch_bounds__(512)
void gemm_pd_kernel(const unsigned short* __restrict__ fb,
                    const float* __restrict__ sq,
                    __half* __restrict__ pdh, int b, int d) {
  __shared__ char smem[131072];        // 2 x (A 32KB + B 32KB) double buffer
  const int t = threadIdx.x;           // 0..511
  const int lane = t & 63;
  const int wave = t >> 6;             // 0..7
  const int wm = wave >> 2, wn = wave & 3;
  const int rowBase = blockIdx.y * 256;
  const int colBase = blockIdx.x * 256;
  const int l15 = lane & 15, l4 = lane >> 4;
  const int rsw = l15 & 7;
  const int nt = d >> 6;               // K-tiles of 64

  f32x4 acc[8][4] = {};

  auto stage_tile = [&](int bufOff, int kt) {
#pragma unroll
    for (int half = 0; half < 2; ++half) {
#pragma unroll
      for (int ab = 0; ab < 2; ++ab) {
#pragma unroll
        for (int i = 0; i < 2; ++i) {
          const int c = half * 1024 + i * 512 + t;   // 16B chunk id
          const int r = c >> 3;
          const int us = (c & 7) ^ (r & 7);          // pre-swizzled source unit
          const int gbase = (ab == 0) ? rowBase : colBase;
          gload_lds16(fb + (size_t)(gbase + r) * d + kt * 64 + us * 8,
                      smem + bufOff + ab * 32768 + c * 16);
        }
      }
    }
  };

  int curOff = 0;
  stage_tile(0, 0);

  for (int kt = 0; kt < nt; ++kt) {
    if (kt + 1 < nt) {
      stage_tile(curOff ^ 65536, kt + 1);
      asm volatile("s_waitcnt vmcnt(8)" ::: "memory");  // cur tile landed; next stays in flight
    } else {
      asm volatile("s_waitcnt vmcnt(0)" ::: "memory");
    }
    __builtin_amdgcn_s_barrier();
    __builtin_amdgcn_sched_barrier(0);

    const unsigned short* smA = (const unsigned short*)(smem + curOff);
    const unsigned short* smB = (const unsigned short*)(smem + curOff + 32768);
#pragma unroll
    for (int ks = 0; ks < 2; ++ks) {
      short8 bf[4];
#pragma unroll
      for (int nn = 0; nn < 4; ++nn)
        bf[nn] = *(const short8*)&smB[(wn * 64 + nn * 16 + l15) * 64 + (((ks * 4 + l4) ^ rsw) * 8)];
#pragma unroll
      for (int m = 0; m < 8; ++m) {
        short8 af = *(const short8*)&smA[(wm * 128 + m * 16 + l15) * 64 + (((ks * 4 + l4) ^ rsw) * 8)];
#pragma unroll
        for (int nn = 0; nn < 4; ++nn)
          acc[m][nn] = __builtin_amdgcn_mfma_f32_16x16x32_bf16(af, bf[nn], acc[m][nn], 0, 0, 0);
      }
    }
    __builtin_amdgcn_sched_barrier(0);
    __builtin_amdgcn_s_barrier();
    __builtin_amdgcn_sched_barrier(0);
    curOff ^= 65536;
  }

  // ---- stage d^2 tile into swizzled LDS (dbuf region reusable: 128KB = 256x256 fp16) ----
  unsigned short* tileC = (unsigned short*)smem;
#pragma unroll
  for (int m = 0; m < 8; ++m) {
    const int r0l = wm * 128 + m * 16 + l4 * 4;      // local row base (4 rows)
    const int gr0 = rowBase + r0l;
    const float sqr0 = sq[gr0], sqr1 = sq[gr0 + 1], sqr2 = sq[gr0 + 2], sqr3 = sq[gr0 + 3];
#pragma unroll
    for (int nn = 0; nn < 4; ++nn) {
      const int cl = wn * 64 + nn * 16 + l15;        // local col
      const int gc = colBase + cl;
      const float sqc = sq[gc];
      float d20 = fmaxf(sqr0 + sqc - 2.0f * acc[m][nn][0], 0.0f);
      float d21 = fmaxf(sqr1 + sqc - 2.0f * acc[m][nn][1], 0.0f);
      float d22 = fmaxf(sqr2 + sqc - 2.0f * acc[m][nn][2], 0.0f);
      float d23 = fmaxf(sqr3 + sqc - 2.0f * acc[m][nn][3], 0.0f);
      unsigned short b0 = (gr0 == gc) ? (unsigned short)0x7C00 : f2h_bits(d20);
      unsigned short b1 = (gr0 + 1 == gc) ? (unsigned short)0x7C00 : f2h_bits(d21);
      unsigned short b2 = (gr0 + 2 == gc) ? (unsigned short)0x7C00 : f2h_bits(d22);
      unsigned short b3 = (gr0 + 3 == gc) ? (unsigned short)0x7C00 : f2h_bits(d23);
#pragma unroll
      for (int rg = 0; rg < 4; ++rg) {
        const int rl = r0l + rg;
        const int dw = rl * 128 + (cl >> 1);
        const int phys = dw ^ (((rl >> 2) & 3) << 3);
        unsigned short bits = (rg == 0) ? b0 : (rg == 1) ? b1 : (rg == 2) ? b2 : b3;
        tileC[phys * 2 + (cl & 1)] = bits;
      }
    }
  }
  __syncthreads();

  // ---- coalesced row-major stores: 32 iters x (512 thr x 8B) = 128 KB ----
#pragma unroll
  for (int it2 = 0; it2 < 32; ++it2) {
    const int rl = it2 * 8 + (t >> 6);               // local row
    const int dwb = rl * 128 + (t & 63) * 2;         // even dword base
    const int phys = dwb ^ (((rl >> 2) & 3) << 3);   // XOR keeps dword pair adjacent
    const unsigned long long v = *(const unsigned long long*)((const char*)smem + (size_t)phys * 4);
    *(unsigned long long*)((char*)pdh + ((size_t)(rowBase + rl) * b + colBase + (t & 63) * 4) * 2) = v;
  }
}

// ---------- kernel 3: wave-per-row top-10 select + loss + last-block reduce ----------
// Last block reproduces the final reduce in the identical summation order ->
// bit-identical output, one fewer dispatch. Plain (cached) pd loads.
// Requires b == 4096 (8 chunks x 64 lanes x 8), C == 128.
__global__ __launch_bounds__(256, 2)
void topk_loss_kernel(const __half* __restrict__ pdh,
                      const float* __restrict__ pi, const float* __restrict__ pj,
                      const int* __restrict__ labels,
                      float* __restrict__ rowsum,
                      unsigned* __restrict__ counter,
                      float* __restrict__ out,
                      int n, int C, int b) {
  __shared__ unsigned lastFlag;
  __shared__ float wredf[4];
  const int t = threadIdx.x, lane = t & 63, wave = t >> 6;
  const int row = blockIdx.x * 4 + wave;

  // ---- Phase A: load row of packed (fp16 d2, idx); top-10 by repeated wave argmin ----
  const ushort8* rowp = (const ushort8*)(pdh + (size_t)row * b);
  unsigned vv[8][8];
  unsigned cmin[8];
#pragma unroll
  for (int ch = 0; ch < 8; ++ch) {
    ushort8 h = rowp[ch * 64 + lane];
    unsigned mn = 0xFFFFFFFFu;
#pragma unroll
    for (int j = 0; j < 8; ++j) {
      unsigned pk = ((unsigned)h[j] << 16) | (unsigned)(ch * 512 + lane * 8 + j);
      vv[ch][j] = pk;
      mn = min(mn, pk);
    }
    cmin[ch] = mn;
  }

  unsigned key[NSEL];   // packed (fp16 d2 | idx) of the 10 nearest, ascending
#pragma unroll
  for (int r = 0; r < NSEL; ++r) {
    unsigned best = cmin[0];
#pragma unroll
    for (int ch = 1; ch < 8; ++ch) best = min(best, cmin[ch]);
#pragma unroll
    for (int o = 32; o; o >>= 1) {
      unsigned q = __shfl_xor(best, o, 64);
      best = min(best, q);
    }
    key[r] = best;
    const int idx = (int)(best & 0xFFFFu);
    if (((idx >> 3) & 63) == lane) {       // owner invalidates + rebuilds its chunk-min
      const int ch = idx >> 9, jj = idx & 7;
#pragma unroll
      for (int cc = 0; cc < 8; ++cc) {
        if (cc == ch) {
          unsigned mn = 0xFFFFFFFFu;
#pragma unroll
          for (int j = 0; j < 8; ++j) {
            if (j == jj) vv[cc][j] = 0xFFFFFFFFu;
            mn = min(mn, vv[cc][j]);
          }
          cmin[cc] = mn;
        }
      }
    }
  }

  // ---- Phase B: radius + masked contributions (prob dot only on label match) ----
  const float r0 = sqrtf(h2f_bits((unsigned short)(key[0] >> 16)));   // 1-NN distance
  const float inv_r0 = 1.0f / r0;
  const int ri = (row < n) ? row : row - n;
  const int li = labels[ri];
  const float* pme = (row < n) ? (pi + (size_t)row * C) : (pj + (size_t)(row - n) * C);
  const float pr0 = pme[lane], pr1 = pme[lane + 64];

  float tot = 0.f;
#pragma unroll
  for (int k = 0; k < NSEL; ++k) {
    const int j = (int)(key[k] & 0xFFFFu);
    const int rj = (j < n) ? j : j - n;
    const int lj = labels[rj];
    const bool m = (li != -1) & (lj != -1) & (li == lj) & (ri != rj);
    if (m) {   // identical across lanes -> uniform branch; ~0.08 hits/row expected
      const float* q = (j < n) ? (pi + (size_t)j * C) : (pj + (size_t)(j - n) * C);
      float part = pr0 * q[lane] + pr1 * q[lane + 64];
#pragma unroll
      for (int o = 32; o; o >>= 1) part += __shfl_xor(part, o, 64);
      const float pd = sqrtf(h2f_bits((unsigned short)(key[k] >> 16)));
      const float w = 1.0f - fminf(fmaxf((pd - r0) * inv_r0, 0.0f), 1.0f);
      tot += w * part;
    }
  }
  if (lane == 0) rowsum[row] = tot;

  // ---- last-block final reduce (bit-identical order to the old kernel 4) ----
  __syncthreads();
  if (t == 0) {
    __threadfence();
    const unsigned old = atomicAdd(counter, 1u);
    lastFlag = (old == (unsigned)(b / 4 - 1)) ? 1u : 0u;
  }
  __syncthreads();
  if (lastFlag) {
    __threadfence();
    float s = 0.f;
    for (int c = t; c < b; c += 256) s += rowsum[c];
#pragma unroll
    for (int o = 32; o; o >>= 1) s += __shfl_xor(s, o, 64);
    if (lane == 0) wredf[wave] = s;
    __syncthreads();
    if (t == 0) {
      float tt = ((wredf[0] + wredf[1]) + wredf[2]) + wredf[3];
      out[0] = tt / ((float)b * (float)b);
    }
  }
}

extern "C" void kernel_launch(void* const* d_in, const int* in_sizes, int n_in,
                              void* d_out, int out_size, void* d_ws, size_t ws_size,
                              hipStream_t stream) {
  const float* zi = (const float*)d_in[0];
  const float* zj = (const float*)d_in[1];
  const float* pi = (const float*)d_in[2];
  const float* pj = (const float*)d_in[3];
  const int* labels = (const int*)d_in[4];

  const int n = in_sizes[4];          // 2048
  const int d = in_sizes[0] / n;      // 512
  const int C = in_sizes[2] / n;      // 128
  const int b = 2 * n;                // 4096

  char* ws = (char*)d_ws;
  size_t off = 0;
  unsigned short* fb = (unsigned short*)(ws + off);
  off += ((size_t)b * d * 2 + 255) & ~(size_t)255;
  float* sq = (float*)(ws + off);
  off += ((size_t)b * 4 + 255) & ~(size_t)255;
  float* rowsum = (float*)(ws + off);
  off += ((size_t)b * 4 + 255) & ~(size_t)255;
  unsigned* counter = (unsigned*)(ws + off);
  off += 256;
  __half* pdh = (__half*)(ws + off);
  off += (size_t)b * b * 2;
  if (ws_size < off) return;  // workspace too small — bail rather than corrupt

  prep_kernel<<<b, 256, 0, stream>>>(zi, zj, fb, sq, counter, n, d);
  dim3 grid(b / 256, b / 256);
  gemm_pd_kernel<<<grid, 512, 0, stream>>>(fb, sq, pdh, b, d);
  topk_loss_kernel<<<b / 4, 256, 0, stream>>>(pdh, pi, pj, labels, rowsum, counter,
                                              (float*)d_out, n, C, b);
}

// Round 17
// 52.441 us; speedup vs baseline: 1.3274x; 1.2967x over previous
//
#include <hip/hip_runtime.h>
#include <hip/hip_bf16.h>
#include <hip/hip_fp16.h>
#include <cstdint>
#include <cstddef>

typedef __attribute__((ext_vector_type(8))) short short8;
typedef __attribute__((ext_vector_type(8))) unsigned short ushort8;
typedef __attribute__((ext_vector_type(4))) float f32x4;

#define NSEL 10   // top-10 by pd (w monotone in pd); key[0] also gives radius

__device__ __forceinline__ void gload_lds16(const void* g, void* l) {
  typedef const __attribute__((address_space(1))) void* gp_t;
  typedef __attribute__((address_space(3))) void* lp_t;
  __builtin_amdgcn_global_load_lds((gp_t)(unsigned long long)(uintptr_t)g,
                                   (lp_t)(unsigned int)(unsigned long long)(uintptr_t)l,
                                   16, 0, 0);
}

__device__ __forceinline__ unsigned short f2h_bits(float f) {
  __half h = __float2half(f);
  return *reinterpret_cast<unsigned short*>(&h);
}

__device__ __forceinline__ float h2f_bits(unsigned short us) {
  __half h = *reinterpret_cast<__half*>(&us);
  return __half2float(h);
}

// ---------- kernel 1: bf16 cast of feats + fp32 row squared-norms ----------
__global__ __launch_bounds__(256)
void prep_kernel(const float* __restrict__ zi, const float* __restrict__ zj,
                 unsigned short* __restrict__ fb, float* __restrict__ sq,
                 int n, int d) {
  __shared__ float wred[4];
  const int row = blockIdx.x;
  const int t = threadIdx.x, lane = t & 63, wave = t >> 6;
  const float* src = (row < n) ? (zi + (size_t)row * d) : (zj + (size_t)(row - n) * d);
  float s = 0.f;
  for (int c = t; c < d; c += 256) {
    float v = src[c];
    s += v * v;
    __hip_bfloat16 h = __float2bfloat16(v);
    fb[(size_t)row * d + c] = *reinterpret_cast<const unsigned short*>(&h);
  }
#pragma unroll
  for (int o = 32; o; o >>= 1) s += __shfl_xor(s, o, 64);
  if (lane == 0) wred[wave] = s;
  __syncthreads();
  if (t == 0) sq[row] = ((wred[0] + wred[1]) + wred[2]) + wred[3];
}

// ---------- kernel 2: 256x256 counted-vmcnt double-buffered bf16 MFMA GEMM ----------
// (R14 form — best measured.)
__global__ __launch_bounds__(512)
void gemm_pd_kernel(const unsigned short* __restrict__ fb,
                    const float* __restrict__ sq,
                    __half* __restrict__ pdh, int b, int d) {
  __shared__ char smem[131072];        // 2 x (A 32KB + B 32KB) double buffer
  const int t = threadIdx.x;           // 0..511
  const int lane = t & 63;
  const int wave = t >> 6;             // 0..7
  const int wm = wave >> 2, wn = wave & 3;
  const int rowBase = blockIdx.y * 256;
  const int colBase = blockIdx.x * 256;
  const int l15 = lane & 15, l4 = lane >> 4;
  const int rsw = l15 & 7;
  const int nt = d >> 6;               // K-tiles of 64

  f32x4 acc[8][4] = {};

  auto stage_tile = [&](int bufOff, int kt) {
#pragma unroll
    for (int half = 0; half < 2; ++half) {
#pragma unroll
      for (int ab = 0; ab < 2; ++ab) {
#pragma unroll
        for (int i = 0; i < 2; ++i) {
          const int c = half * 1024 + i * 512 + t;   // 16B chunk id
          const int r = c >> 3;
          const int us = (c & 7) ^ (r & 7);          // pre-swizzled source unit
          const int gbase = (ab == 0) ? rowBase : colBase;
          gload_lds16(fb + (size_t)(gbase + r) * d + kt * 64 + us * 8,
                      smem + bufOff + ab * 32768 + c * 16);
        }
      }
    }
  };

  int curOff = 0;
  stage_tile(0, 0);

  for (int kt = 0; kt < nt; ++kt) {
    if (kt + 1 < nt) {
      stage_tile(curOff ^ 65536, kt + 1);
      asm volatile("s_waitcnt vmcnt(8)" ::: "memory");  // cur tile landed; next stays in flight
    } else {
      asm volatile("s_waitcnt vmcnt(0)" ::: "memory");
    }
    __builtin_amdgcn_s_barrier();
    __builtin_amdgcn_sched_barrier(0);

    const unsigned short* smA = (const unsigned short*)(smem + curOff);
    const unsigned short* smB = (const unsigned short*)(smem + curOff + 32768);
#pragma unroll
    for (int ks = 0; ks < 2; ++ks) {
      short8 bf[4];
#pragma unroll
      for (int nn = 0; nn < 4; ++nn)
        bf[nn] = *(const short8*)&smB[(wn * 64 + nn * 16 + l15) * 64 + (((ks * 4 + l4) ^ rsw) * 8)];
#pragma unroll
      for (int m = 0; m < 8; ++m) {
        short8 af = *(const short8*)&smA[(wm * 128 + m * 16 + l15) * 64 + (((ks * 4 + l4) ^ rsw) * 8)];
#pragma unroll
        for (int nn = 0; nn < 4; ++nn)
          acc[m][nn] = __builtin_amdgcn_mfma_f32_16x16x32_bf16(af, bf[nn], acc[m][nn], 0, 0, 0);
      }
    }
    __builtin_amdgcn_sched_barrier(0);
    __builtin_amdgcn_s_barrier();
    __builtin_amdgcn_sched_barrier(0);
    curOff ^= 65536;
  }

  // ---- stage d^2 tile into swizzled LDS (dbuf region reusable: 128KB = 256x256 fp16) ----
  unsigned short* tileC = (unsigned short*)smem;
#pragma unroll
  for (int m = 0; m < 8; ++m) {
    const int r0l = wm * 128 + m * 16 + l4 * 4;      // local row base (4 rows)
    const int gr0 = rowBase + r0l;
    const float sqr0 = sq[gr0], sqr1 = sq[gr0 + 1], sqr2 = sq[gr0 + 2], sqr3 = sq[gr0 + 3];
#pragma unroll
    for (int nn = 0; nn < 4; ++nn) {
      const int cl = wn * 64 + nn * 16 + l15;        // local col
      const int gc = colBase + cl;
      const float sqc = sq[gc];
      float d20 = fmaxf(sqr0 + sqc - 2.0f * acc[m][nn][0], 0.0f);
      float d21 = fmaxf(sqr1 + sqc - 2.0f * acc[m][nn][1], 0.0f);
      float d22 = fmaxf(sqr2 + sqc - 2.0f * acc[m][nn][2], 0.0f);
      float d23 = fmaxf(sqr3 + sqc - 2.0f * acc[m][nn][3], 0.0f);
      unsigned short b0 = (gr0 == gc) ? (unsigned short)0x7C00 : f2h_bits(d20);
      unsigned short b1 = (gr0 + 1 == gc) ? (unsigned short)0x7C00 : f2h_bits(d21);
      unsigned short b2 = (gr0 + 2 == gc) ? (unsigned short)0x7C00 : f2h_bits(d22);
      unsigned short b3 = (gr0 + 3 == gc) ? (unsigned short)0x7C00 : f2h_bits(d23);
#pragma unroll
      for (int rg = 0; rg < 4; ++rg) {
        const int rl = r0l + rg;
        const int dw = rl * 128 + (cl >> 1);
        const int phys = dw ^ (((rl >> 2) & 3) << 3);
        unsigned short bits = (rg == 0) ? b0 : (rg == 1) ? b1 : (rg == 2) ? b2 : b3;
        tileC[phys * 2 + (cl & 1)] = bits;
      }
    }
  }
  __syncthreads();

  // ---- coalesced row-major stores: 32 iters x (512 thr x 8B) = 128 KB ----
#pragma unroll
  for (int it2 = 0; it2 < 32; ++it2) {
    const int rl = it2 * 8 + (t >> 6);               // local row
    const int dwb = rl * 128 + (t & 63) * 2;         // even dword base
    const int phys = dwb ^ (((rl >> 2) & 3) << 3);   // XOR keeps dword pair adjacent
    const unsigned long long v = *(const unsigned long long*)((const char*)smem + (size_t)phys * 4);
    *(unsigned long long*)((char*)pdh + ((size_t)(rowBase + rl) * b + colBase + (t & 63) * 4) * 2) = v;
  }
}

// ---------- kernel 3: one-wave-per-block top-10 select + loss ----------
// 64-thread blocks (1 wave = 1 row): no inter-wave sync exists in this kernel,
// so smaller blocks raise resident waves/SIMD (2 -> ~4) and hide the serial
// shfl-chain + row-load latency. launch_bounds(64,4) caps VGPR at 128 (vv fits).
// Requires b == 4096 (8 chunks x 64 lanes x 8), C == 128.
__global__ __launch_bounds__(64, 4)
void topk_loss_kernel(const __half* __restrict__ pdh,
                      const float* __restrict__ pi, const float* __restrict__ pj,
                      const int* __restrict__ labels,
                      float* __restrict__ rowsum,
                      int n, int C, int b) {
  const int lane = threadIdx.x & 63;
  const int row = blockIdx.x;

  // ---- Phase A: load row of packed (fp16 d2, idx); top-10 by repeated wave argmin ----
  const ushort8* rowp = (const ushort8*)(pdh + (size_t)row * b);
  unsigned vv[8][8];
  unsigned cmin[8];
#pragma unroll
  for (int ch = 0; ch < 8; ++ch) {
    ushort8 h = rowp[ch * 64 + lane];
    unsigned mn = 0xFFFFFFFFu;
#pragma unroll
    for (int j = 0; j < 8; ++j) {
      unsigned pk = ((unsigned)h[j] << 16) | (unsigned)(ch * 512 + lane * 8 + j);
      vv[ch][j] = pk;
      mn = min(mn, pk);
    }
    cmin[ch] = mn;
  }

  unsigned key[NSEL];   // packed (fp16 d2 | idx) of the 10 nearest, ascending
#pragma unroll
  for (int r = 0; r < NSEL; ++r) {
    unsigned best = cmin[0];
#pragma unroll
    for (int ch = 1; ch < 8; ++ch) best = min(best, cmin[ch]);
#pragma unroll
    for (int o = 32; o; o >>= 1) {
      unsigned q = __shfl_xor(best, o, 64);
      best = min(best, q);
    }
    key[r] = best;
    const int idx = (int)(best & 0xFFFFu);
    if (((idx >> 3) & 63) == lane) {       // owner invalidates + rebuilds its chunk-min
      const int ch = idx >> 9, jj = idx & 7;
#pragma unroll
      for (int cc = 0; cc < 8; ++cc) {
        if (cc == ch) {
          unsigned mn = 0xFFFFFFFFu;
#pragma unroll
          for (int j = 0; j < 8; ++j) {
            if (j == jj) vv[cc][j] = 0xFFFFFFFFu;
            mn = min(mn, vv[cc][j]);
          }
          cmin[cc] = mn;
        }
      }
    }
  }

  // ---- Phase B: radius + masked contributions (prob dot only on label match) ----
  const float r0 = sqrtf(h2f_bits((unsigned short)(key[0] >> 16)));   // 1-NN distance
  const float inv_r0 = 1.0f / r0;
  const int ri = (row < n) ? row : row - n;
  const int li = labels[ri];
  const float* pme = (row < n) ? (pi + (size_t)row * C) : (pj + (size_t)(row - n) * C);
  const float pr0 = pme[lane], pr1 = pme[lane + 64];

  float tot = 0.f;
#pragma unroll
  for (int k = 0; k < NSEL; ++k) {
    const int j = (int)(key[k] & 0xFFFFu);
    const int rj = (j < n) ? j : j - n;
    const int lj = labels[rj];
    const bool m = (li != -1) & (lj != -1) & (li == lj) & (ri != rj);
    if (m) {   // identical across lanes -> uniform branch; ~0.08 hits/row expected
      const float* q = (j < n) ? (pi + (size_t)j * C) : (pj + (size_t)(j - n) * C);
      float part = pr0 * q[lane] + pr1 * q[lane + 64];
#pragma unroll
      for (int o = 32; o; o >>= 1) part += __shfl_xor(part, o, 64);
      const float pd = sqrtf(h2f_bits((unsigned short)(key[k] >> 16)));
      const float w = 1.0f - fminf(fmaxf((pd - r0) * inv_r0, 0.0f), 1.0f);
      tot += w * part;
    }
  }
  if (lane == 0) rowsum[row] = tot;
}

// ---------- kernel 4: deterministic final reduce ----------
__global__ __launch_bounds__(256)
void final_reduce_kernel(const float* __restrict__ rowsum, float* __restrict__ out, int b) {
  __shared__ float wredf[4];
  const int t = threadIdx.x, lane = t & 63, wave = t >> 6;
  float s = 0.f;
  for (int c = t; c < b; c += 256) s += rowsum[c];
#pragma unroll
  for (int o = 32; o; o >>= 1) s += __shfl_xor(s, o, 64);
  if (lane == 0) wredf[wave] = s;
  __syncthreads();
  if (t == 0) {
    float tot = ((wredf[0] + wredf[1]) + wredf[2]) + wredf[3];
    out[0] = tot / ((float)b * (float)b);
  }
}

extern "C" void kernel_launch(void* const* d_in, const int* in_sizes, int n_in,
                              void* d_out, int out_size, void* d_ws, size_t ws_size,
                              hipStream_t stream) {
  const float* zi = (const float*)d_in[0];
  const float* zj = (const float*)d_in[1];
  const float* pi = (const float*)d_in[2];
  const float* pj = (const float*)d_in[3];
  const int* labels = (const int*)d_in[4];

  const int n = in_sizes[4];          // 2048
  const int d = in_sizes[0] / n;      // 512
  const int C = in_sizes[2] / n;      // 128
  const int b = 2 * n;                // 4096

  char* ws = (char*)d_ws;
  size_t off = 0;
  unsigned short* fb = (unsigned short*)(ws + off);
  off += ((size_t)b * d * 2 + 255) & ~(size_t)255;
  float* sq = (float*)(ws + off);
  off += ((size_t)b * 4 + 255) & ~(size_t)255;
  float* rowsum = (float*)(ws + off);
  off += ((size_t)b * 4 + 255) & ~(size_t)255;
  __half* pdh = (__half*)(ws + off);
  off += (size_t)b * b * 2;
  if (ws_size < off) return;  // workspace too small — bail rather than corrupt

  prep_kernel<<<b, 256, 0, stream>>>(zi, zj, fb, sq, n, d);
  dim3 grid(b / 256, b / 256);
  gemm_pd_kernel<<<grid, 512, 0, stream>>>(fb, sq, pdh, b, d);
  topk_loss_kernel<<<b, 64, 0, stream>>>(pdh, pi, pj, labels, rowsum, n, C, b);
  final_reduce_kernel<<<1, 256, 0, stream>>>(rowsum, (float*)d_out, b);
}